// Round 10
// baseline (346.991 us; speedup 1.0000x reference)
//
#include <hip/hip_runtime.h>

// B=4, L=2048, D=1024, H=16, HD=64. Inputs fp32, output fp32.
// All matmul math via mfma_f32_16x16x32_bf16, fp32 accumulation.
// v13 = best-of composition: attn is byte-exact v8 (92.1us measured: paired
// q-tiles, 4 waves x 32 q-rows, LDS-staged K/V dbuf + XOR swizzle,
// XCD-grouping, interleaved max accumulation, unconditional rescale placed
// inside the P^T LDS round-trip) + v12's merged prologue (setup+cvt4+ln_pre
// in one kernel, -10.5us) + 128^2 dbuf GEMMs with XCD swizzle.
// ws: h bf16 | q bf16 [bh][l][64] | k bf16 [bh][l][64] | vT bf16 [bh][d][L]
//     | attn bf16 [bh][l][64] | W3+Wo bf16 | proj fp32 | lengths.

#define Bq 4
#define Lq 2048
#define Dq 1024
#define Hq 16
#define HDq 64
#define Mq (Bq * Lq)  // 8192

typedef __attribute__((ext_vector_type(8))) short short8;
typedef __attribute__((ext_vector_type(4))) float f32x4;
typedef __attribute__((address_space(3))) unsigned char lds_byte;
typedef __attribute__((address_space(1))) unsigned char gbl_byte;

__device__ __forceinline__ unsigned short f2b(float f) {
    unsigned int u = __float_as_uint(f);
    unsigned int r = (u + 0x7fffu + ((u >> 16) & 1u)) >> 16;  // RNE
    return (unsigned short)r;
}
__device__ __forceinline__ float b2f(unsigned short u) {
    return __uint_as_float(((unsigned int)u) << 16);
}
__device__ __forceinline__ unsigned int packbf(float lo, float hi) {
    return (unsigned int)f2b(lo) | ((unsigned int)f2b(hi) << 16);
}

#define GLL16(gsrc, ldst)                                              \
    __builtin_amdgcn_global_load_lds((const gbl_byte*)(gsrc),          \
                                     (lds_byte*)(ldst), 16, 0, 0)

#define MFMA_BF16(A, B, C) \
    __builtin_amdgcn_mfma_f32_16x16x32_bf16((A), (B), (C), 0, 0, 0)

// --------------------------------------------------------------- prologue ---
// blocks [0,4096): cvt4 (f32->bf16 of Wq|Wk|Wv|Wo into W3 buffer)
// blocks [4096,12288): ln_pre row = bid-4096
// block 12288: setup (first-padded-column per batch row)
__global__ __launch_bounds__(256) void prologue_kernel(
    const float* __restrict__ s0, const float* __restrict__ s1,
    const float* __restrict__ s2, const float* __restrict__ s3,
    unsigned short* __restrict__ dst, const float* __restrict__ x,
    const float* __restrict__ g, const float* __restrict__ bb,
    unsigned short* __restrict__ out, const unsigned char* __restrict__ m8,
    int* __restrict__ lengths) {
    const int bid = blockIdx.x;
    const int tid = threadIdx.x;
    if (bid < 4096) {
        const int region = bid >> 10;  // 1024 blocks per weight
        const int i = (bid & 1023) * 256 + tid;
        const float* src = (region == 0) ? s0 : (region == 1) ? s1
                           : (region == 2) ? s2 : s3;
        float4 v = ((const float4*)src)[i];
        ushort4 o;
        o.x = f2b(v.x); o.y = f2b(v.y); o.z = f2b(v.z); o.w = f2b(v.w);
        ((ushort4*)dst)[(size_t)region * (Dq * Dq / 4) + i] = o;
        return;
    }
    if (bid < 4096 + Mq) {
        const int row = bid - 4096;
        float4 u = ((const float4*)x)[(size_t)row * 256 + tid];
        float s = u.x + u.y + u.z + u.w;
        float ss = u.x * u.x + u.y * u.y + u.z * u.z + u.w * u.w;
#pragma unroll
        for (int off = 32; off > 0; off >>= 1) {
            s += __shfl_xor(s, off);
            ss += __shfl_xor(ss, off);
        }
        __shared__ float sred[4], ssred[4];
        const int w = tid >> 6, lane = tid & 63;
        if (lane == 0) { sred[w] = s; ssred[w] = ss; }
        __syncthreads();
        s = sred[0] + sred[1] + sred[2] + sred[3];
        ss = ssred[0] + ssred[1] + ssred[2] + ssred[3];
        const float mean = s * (1.f / Dq);
        const float rstd = rsqrtf(ss * (1.f / Dq) - mean * mean + 1e-5f);
        float4 gv = ((const float4*)g)[tid];
        float4 bv = ((const float4*)bb)[tid];
        ushort4 o;
        o.x = f2b((u.x - mean) * rstd * gv.x + bv.x);
        o.y = f2b((u.y - mean) * rstd * gv.y + bv.y);
        o.z = f2b((u.z - mean) * rstd * gv.z + bv.z);
        o.w = f2b((u.w - mean) * rstd * gv.w + bv.w);
        ((ushort4*)out)[(size_t)row * 256 + tid] = o;
        return;
    }
    // setup
    __shared__ int bad;
    __shared__ int fo[4];
    if (tid == 0) bad = 0;
    if (tid < 4) fo[tid] = Lq;
    __syncthreads();
    for (int i = tid; i < Bq * Lq; i += 256) {
        unsigned char v = m8[i];
        if (v) {
            int r = i >> 11, c = i & (Lq - 1);
            atomicMin(&fo[r], c);
            if (c < Lq / 2) atomicOr(&bad, 1);
            else if (c < Lq - 1 && m8[i + 1] == 0) atomicOr(&bad, 1);
        }
    }
    __syncthreads();
    int anyone = (fo[0] < Lq) | (fo[1] < Lq) | (fo[2] < Lq) | (fo[3] < Lq);
    bool use8 = (bad == 0) && anyone;
    if (!use8) {
        __syncthreads();
        if (tid < 4) fo[tid] = Lq;
        __syncthreads();
        const int* m32 = (const int*)m8;
        for (int i = tid; i < Bq * Lq; i += 256) {
            if (m32[i] != 0) atomicMin(&fo[i >> 11], i & (Lq - 1));
        }
        __syncthreads();
    }
    if (tid < 4) lengths[tid] = fo[tid];
}

// -------------------------------------------------------- fused QKV GEMM ----
// C[8192][3072] = h @ [Wq;Wk;Wv]^T + bias. Q (pre-scaled by 1/8), K ->
// head-split [bh][l][64]; V -> transposed [bh][d][L]. XCD-swizzled blocks.
// Double-buffered LDS: STAGE(k+1) issued before compute(k); one barrier/iter.
__global__ __launch_bounds__(256) void qkv_gemm_kernel(
    const unsigned short* __restrict__ A, const unsigned short* __restrict__ W3,
    const float* __restrict__ bq, const float* __restrict__ bk,
    const float* __restrict__ bv, unsigned short* __restrict__ Qo,
    unsigned short* __restrict__ Ko, unsigned short* __restrict__ Vto) {
    __shared__ unsigned short As[2][128][32];
    __shared__ unsigned short Bs[2][128][32];
    const int tid = threadIdx.x;
    const int w = tid >> 6, lane = tid & 63;
    const int lm = lane & 15, lq = lane >> 4;
    // XCD-aware bijective swizzle (total blocks = 24*64 = 1536, %8 == 0)
    const int lin = blockIdx.y * 24 + blockIdx.x;
    const int swz = (lin & 7) * (1536 / 8) + (lin >> 3);
    const int m0 = (swz / 24) << 7, n0 = (swz % 24) << 7;  // n0 in [0,3072)
    const int wm = (w >> 1) << 6, wn = (w & 1) << 6;
    f32x4 acc[4][4];
#pragma unroll
    for (int i = 0; i < 4; ++i)
#pragma unroll
        for (int j = 0; j < 4; ++j) acc[i][j] = (f32x4){0.f, 0.f, 0.f, 0.f};

#define QKV_STAGE(BUF, K0)                                              \
    {                                                                   \
        _Pragma("unroll")                                               \
        for (int j = 0; j < 2; ++j) {                                   \
            const int base = j * 256 + w * 64;                          \
            const int slot = base + lane;                               \
            const int row = slot >> 2, c = slot & 3;                    \
            GLL16(A + (size_t)(m0 + row) * Dq + (K0) + c * 8,           \
                  (unsigned short*)As[BUF] + base * 8);                 \
            GLL16(W3 + (size_t)(n0 + row) * Dq + (K0) + c * 8,          \
                  (unsigned short*)Bs[BUF] + base * 8);                 \
        }                                                               \
    }

    QKV_STAGE(0, 0);
    __syncthreads();  // tile 0 resident
    for (int k0 = 0; k0 < Dq; k0 += 32) {
        const int cur = (k0 >> 5) & 1;
        if (k0 + 32 < Dq) QKV_STAGE(cur ^ 1, k0 + 32);  // prefetch next
        short8 af[4], bf[4];
#pragma unroll
        for (int t = 0; t < 4; ++t)
            af[t] = *(const short8*)&As[cur][wm + t * 16 + lm][lq * 8];
#pragma unroll
        for (int t = 0; t < 4; ++t)
            bf[t] = *(const short8*)&Bs[cur][wn + t * 16 + lm][lq * 8];
#pragma unroll
        for (int mt = 0; mt < 4; ++mt)
#pragma unroll
            for (int nt = 0; nt < 4; ++nt)
                acc[mt][nt] = __builtin_amdgcn_mfma_f32_16x16x32_bf16(
                    af[mt], bf[nt], acc[mt][nt], 0, 0, 0);
        __syncthreads();  // drains vmcnt (next tile resident), reads done
    }
#undef QKV_STAGE
    const int region = n0 >> 10;  // 0=Q 1=K 2=V (block-uniform)
    const float* bias = (region == 0) ? bq : (region == 1) ? bk : bv;
    const float scale = (region == 0) ? 0.125f : 1.0f;  // 1/sqrt(HD) into Q
    const int nb = n0 & 1023;
#pragma unroll
    for (int nt = 0; nt < 4; ++nt) {
        const int colb = nb + wn + nt * 16 + lm;  // 0..1023 within region
        const float bval = bias[colb];
#pragma unroll
        for (int mt = 0; mt < 4; ++mt) {
            const int row0 = m0 + wm + mt * 16 + lq * 4;
            const int bidx = row0 >> 11, l0r = row0 & (Lq - 1);
            if (region < 2) {
                unsigned short* dst = (region == 0) ? Qo : Ko;
#pragma unroll
                for (int r = 0; r < 4; ++r)
                    dst[((size_t)(bidx * Hq + (colb >> 6)) * Lq + l0r + r) *
                            HDq + (colb & 63)] =
                        f2b((acc[mt][nt][r] + bval) * scale);
            } else {
                ushort4 o;
                o.x = f2b(acc[mt][nt][0] + bval);
                o.y = f2b(acc[mt][nt][1] + bval);
                o.z = f2b(acc[mt][nt][2] + bval);
                o.w = f2b(acc[mt][nt][3] + bval);
                *(ushort4*)&Vto[((size_t)(bidx * Hq + (colb >> 6)) * HDq +
                                 (colb & 63)) * Lq + l0r] = o;
            }
        }
    }
}

// ------------------------------------------------------------- proj GEMM ----
// Double-buffered LDS with next-tile prefetch, as qkv.
__global__ __launch_bounds__(256) void proj_gemm_kernel(
    const unsigned short* __restrict__ A, const unsigned short* __restrict__ Bw,
    const float* __restrict__ bias, float* __restrict__ Cout) {
    __shared__ unsigned short As[2][128][32];
    __shared__ unsigned short Bs[2][128][32];
    const int tid = threadIdx.x;
    const int w = tid >> 6, lane = tid & 63;
    const int lm = lane & 15, lq = lane >> 4;
    // XCD-aware bijective swizzle (total blocks = 8*64 = 512, %8 == 0)
    const int lin = blockIdx.y * 8 + blockIdx.x;
    const int swz = (lin & 7) * (512 / 8) + (lin >> 3);
    const int m0 = (swz >> 3) << 7, n0 = (swz & 7) << 7;
    const int wm = (w >> 1) << 6, wn = (w & 1) << 6;
    f32x4 acc[4][4];
#pragma unroll
    for (int i = 0; i < 4; ++i)
#pragma unroll
        for (int j = 0; j < 4; ++j) acc[i][j] = (f32x4){0.f, 0.f, 0.f, 0.f};

#define PROJ_STAGE(BUF, K0)                                             \
    {                                                                   \
        _Pragma("unroll")                                               \
        for (int j = 0; j < 2; ++j) {                                   \
            const int base = j * 256 + w * 64;                          \
            const int slot = base + lane;                               \
            const int row = slot >> 2, c = slot & 3;                    \
            const int rr = m0 + row, kk = (K0) + c * 8;                 \
            GLL16(A + ((size_t)((rr >> 11) * Hq + (kk >> 6)) * Lq +     \
                       (rr & (Lq - 1))) * HDq + (kk & 63),              \
                  (unsigned short*)As[BUF] + base * 8);                 \
            GLL16(Bw + (size_t)(n0 + row) * Dq + (K0) + c * 8,          \
                  (unsigned short*)Bs[BUF] + base * 8);                 \
        }                                                               \
    }

    PROJ_STAGE(0, 0);
    __syncthreads();
    for (int k0 = 0; k0 < Dq; k0 += 32) {
        const int cur = (k0 >> 5) & 1;
        if (k0 + 32 < Dq) PROJ_STAGE(cur ^ 1, k0 + 32);
        short8 af[4], bf[4];
#pragma unroll
        for (int t = 0; t < 4; ++t)
            af[t] = *(const short8*)&As[cur][wm + t * 16 + lm][lq * 8];
#pragma unroll
        for (int t = 0; t < 4; ++t)
            bf[t] = *(const short8*)&Bs[cur][wn + t * 16 + lm][lq * 8];
#pragma unroll
        for (int mt = 0; mt < 4; ++mt)
#pragma unroll
            for (int nt = 0; nt < 4; ++nt)
                acc[mt][nt] = __builtin_amdgcn_mfma_f32_16x16x32_bf16(
                    af[mt], bf[nt], acc[mt][nt], 0, 0, 0);
        __syncthreads();
    }
#undef PROJ_STAGE
#pragma unroll
    for (int nt = 0; nt < 4; ++nt) {
        const float bval = bias[n0 + wn + nt * 16 + lm];
#pragma unroll
        for (int mt = 0; mt < 4; ++mt)
#pragma unroll
            for (int r = 0; r < 4; ++r)
                Cout[(size_t)(m0 + wm + mt * 16 + lq * 4 + r) * Dq + n0 + wn +
                     nt * 16 + lm] = acc[mt][nt][r] + bval;
    }
}

// ------------------------------------------------------- MFMA attention -----
// Byte-exact v8 (measured 92.1us): block = (q-tile pair, head, batch), 4
// waves; wave w owns q rows [w*32, w*32+32) of each 128-q tile as two
// 16-strips (q = lane&15). XCD-grouping: all 8 blocks of one (b,h) share an
// XCD -> K/V from its L2. Per kt, block stages K/V^T tiles into
// double-buffered LDS (global_load_lds dwordx4, 16B-chunk XOR swizzle via
// pre-swizzled global source + swizzled ds_read -> conflict-free b128).
// Both strips share one K/V fragment read and one lgkmcnt(0) per kt; the
// rescale VALU sits between the P^T write and its wait (latency filler).
// Max accumulation interleaved in the fill loop (scheduler filler).
// Q pre-scaled by 1/8 upstream; __expf softmax.
__global__ __launch_bounds__(256, 2) void attn_kernel(
    const unsigned short* __restrict__ Qg, const unsigned short* __restrict__ Kg,
    const unsigned short* __restrict__ Vtg, const int* __restrict__ lengths,
    unsigned short* __restrict__ Og) {
    __shared__ unsigned short Kbuf[2][4096];     // 2 x 8KB
    __shared__ unsigned short Vbuf[2][4096];     // 2 x 8KB
    __shared__ unsigned short Ps[4][2][16][72];  // per-wave-strip P^T (18KB)
    // XCD-grouping remap: lin = x + 8y + 128z; xcd = lin&7 (dispatch
    // round-robin); group g = xcd*8 + (sidx&7) so all 8 bx of g share an XCD.
    const int lin = blockIdx.x + (blockIdx.y << 3) + (blockIdx.z << 7);
    const int xcd = lin & 7, sidx = lin >> 3;
    const int grp = xcd * 8 + (sidx & 7);  // 0..63 = (b,h)
    const int bx = sidx >> 3;              // 0..7 q-tile pair index
    const int hh = grp & 15, b = grp >> 4;
    const int tid = threadIdx.x, w = tid >> 6, lane = tid & 63;
    const int lm = lane & 15, lq = lane >> 4;
    const int len = lengths[b];
    const int mxk = (len + 63) >> 6;
    const size_t hb = (size_t)(b * Hq + hh) * Lq * HDq;  // Q,K,O base
    const unsigned short* Vb = Vtg + hb;                  // [d][L]

    // staging: thread covers chunk L = r*256 + w*64 + lane of each 512-chunk
    // (16B) tile; row = L>>3, stored slot = L&7, fetched slot =
    // (L&7) ^ (row&7)  [XOR bijection per row]
    const int srow = w * 8 + (lane >> 3);             // rows 0..31 (r=1: +32)
    const int ssw = (lane & 7) ^ (lane >> 3);         // swizzled source slot
    const unsigned short* pK = Kg + hb + (size_t)srow * HDq + ssw * 8;
    const unsigned short* pV = Vb + (size_t)srow * Lq + ssw * 8;

#define STAGE_KV(BUF, KB)                                                   \
    {                                                                       \
        GLL16(pK + (size_t)(KB)*HDq, &Kbuf[(BUF)][(w * 64) * 8]);           \
        GLL16(pK + (size_t)((KB) + 32) * HDq,                               \
              &Kbuf[(BUF)][(256 + w * 64) * 8]);                            \
        GLL16(pV + (KB), &Vbuf[(BUF)][(w * 64) * 8]);                       \
        GLL16(pV + (size_t)32 * Lq + (KB),                                  \
              &Vbuf[(BUF)][(256 + w * 64) * 8]);                            \
    }

#pragma unroll
    for (int pass = 0; pass < 2; ++pass) {
        const int qt = pass ? bx : (15 - bx);  // pair: total work uniform
        const int l0 = qt << 7;
        // Q fragments: direct register loads
        short8 qf[2][2];
#pragma unroll
        for (int s = 0; s < 2; ++s)
#pragma unroll
            for (int h = 0; h < 2; ++h)
                qf[s][h] = *(const short8*)(Qg + hb +
                    (size_t)(l0 + w * 32 + s * 16 + lm) * HDq + h * 32 + lq * 8);
        f32x4 oacc[2][4];
        float m_i[2], l_i[2];
#pragma unroll
        for (int s = 0; s < 2; ++s) {
            m_i[s] = -1e30f; l_i[s] = 0.f;
#pragma unroll
            for (int t = 0; t < 4; ++t)
                oacc[s][t] = (f32x4){0.f, 0.f, 0.f, 0.f};
        }
        int nkt = 2 * qt + 2;
        if (nkt > mxk) nkt = mxk;
        // prologue: stage kt=0 into buf 0 (nkt >= 2 always since len >= L/2)
        STAGE_KV(0, 0);
        __syncthreads();  // drains vmcnt -> tile 0 resident
        for (int kt = 0; kt < nkt; ++kt) {
            const int kb = kt << 6;
            const int cur = kt & 1;
            if (kt + 1 < nkt) STAGE_KV(cur ^ 1, (kt + 1) << 6);
            // fragments from LDS (swizzled chunk index, conflict-free b128)
            short8 kf[4][2], vf[4][2];
#pragma unroll
            for (int t = 0; t < 4; ++t) {
                const int ro = (t * 16 + lm) * 64;
                const int sx = lm & 7;
#pragma unroll
                for (int h = 0; h < 2; ++h) {
                    const int off = ro + (((h * 4 + lq) ^ sx) << 3);
                    kf[t][h] = *(const short8*)&Kbuf[cur][off];
                    vf[t][h] = *(const short8*)&Vbuf[cur][off];
                }
            }
            f32x4 sc[2][4];
            __builtin_amdgcn_s_setprio(1);
#pragma unroll
            for (int s = 0; s < 2; ++s) {
#pragma unroll
                for (int t = 0; t < 4; ++t) {  // S^T = K Q^T
                    f32x4 z = (f32x4){0.f, 0.f, 0.f, 0.f};
                    z = MFMA_BF16(kf[t][0], qf[s][0], z);
                    z = MFMA_BF16(kf[t][1], qf[s][1], z);
                    sc[s][t] = z;
                }
            }
            __builtin_amdgcn_s_setprio(0);
#pragma unroll
            for (int s = 0; s < 2; ++s) {
                const int qmin = l0 + w * 32 + s * 16;
                float pvv[16];
                float mx = -1e30f;
                if ((kb + 63 <= qmin) && (kb + 63 < len)) {  // interior
#pragma unroll
                    for (int i = 0; i < 16; ++i) {
                        const float v = sc[s][i >> 2][i & 3];
                        pvv[i] = v;
                        mx = fmaxf(mx, v);
                    }
                } else {
                    const int qq = qmin + lm;
#pragma unroll
                    for (int t = 0; t < 4; ++t)
#pragma unroll
                        for (int r = 0; r < 4; ++r) {
                            const int key = kb + t * 16 + lq * 4 + r;
                            float v = sc[s][t][r];
                            if (key > qq || key >= len) v = -1e30f;
                            pvv[t * 4 + r] = v;
                            mx = fmaxf(mx, v);
                        }
                }
                mx = fmaxf(mx, __shfl_xor(mx, 16));
                mx = fmaxf(mx, __shfl_xor(mx, 32));
                const float mnew = fmaxf(m_i[s], mx);
                float psum = 0.f;
#pragma unroll
                for (int i = 0; i < 16; ++i) {
                    const float p = __expf(pvv[i] - mnew);
                    pvv[i] = p;
                    psum += p;
                }
                // P^T C-layout -> B-layout via per-wave-strip LDS scratch
#pragma unroll
                for (int t = 0; t < 4; ++t) {
                    uint2 uu;
                    uu.x = packbf(pvv[t * 4 + 0], pvv[t * 4 + 1]);
                    uu.y = packbf(pvv[t * 4 + 2], pvv[t * 4 + 3]);
                    *(uint2*)&Ps[w][s][lm][t * 16 + lq * 4] = uu;
                }
                psum += __shfl_xor(psum, 16);
                psum += __shfl_xor(psum, 32);
                const float alpha = __expf(m_i[s] - mnew);
                m_i[s] = mnew;
                l_i[s] = l_i[s] * alpha + psum;
#pragma unroll
                for (int t = 0; t < 4; ++t) {
                    oacc[s][t][0] *= alpha; oacc[s][t][1] *= alpha;
                    oacc[s][t][2] *= alpha; oacc[s][t][3] *= alpha;
                }
            }
            asm volatile("s_waitcnt lgkmcnt(0)" ::: "memory");
            __builtin_amdgcn_s_setprio(1);
#pragma unroll
            for (int s = 0; s < 2; ++s) {
                short8 pf0 = *(const short8*)&Ps[w][s][lm][lq * 8];
                short8 pf1 = *(const short8*)&Ps[w][s][lm][32 + lq * 8];
#pragma unroll
                for (int t = 0; t < 4; ++t) {  // O^T += V^T P^T
                    oacc[s][t] = MFMA_BF16(vf[t][0], pf0, oacc[s][t]);
                    oacc[s][t] = MFMA_BF16(vf[t][1], pf1, oacc[s][t]);
                }
            }
            __builtin_amdgcn_s_setprio(0);
            __syncthreads();  // staged kt+1 resident; buf[cur] reads done
        }
#pragma unroll
        for (int s = 0; s < 2; ++s) {
            const float inv = 1.f / l_i[s];
            unsigned short* Ot =
                Og + hb + (size_t)(l0 + w * 32 + s * 16 + lm) * HDq;
#pragma unroll
            for (int t = 0; t < 4; ++t) {
                ushort4 o;
                o.x = f2b(oacc[s][t][0] * inv);
                o.y = f2b(oacc[s][t][1] * inv);
                o.z = f2b(oacc[s][t][2] * inv);
                o.w = f2b(oacc[s][t][3] * inv);
                *(ushort4*)(Ot + t * 16 + lq * 4) = o;
            }
        }
    }
#undef STAGE_KV
}

// ------------------------------------------------------------------- LN 2 ---
__global__ __launch_bounds__(256) void ln_final_kernel(
    const float* __restrict__ pj, const unsigned short* __restrict__ h,
    const float* __restrict__ g, const float* __restrict__ bb,
    float* __restrict__ out) {
    const int row = blockIdx.x, tid = threadIdx.x;
    float4 a = ((const float4*)pj)[(size_t)row * 256 + tid];
    ushort4 hv = ((const ushort4*)h)[(size_t)row * 256 + tid];
    float f0 = a.x + b2f(hv.x), f1 = a.y + b2f(hv.y);
    float f2 = a.z + b2f(hv.z), f3 = a.w + b2f(hv.w);
    float s = f0 + f1 + f2 + f3;
    float ss = f0 * f0 + f1 * f1 + f2 * f2 + f3 * f3;
#pragma unroll
    for (int off = 32; off > 0; off >>= 1) {
        s += __shfl_xor(s, off);
        ss += __shfl_xor(ss, off);
    }
    __shared__ float sred[4], ssred[4];
    const int w = tid >> 6, lane = tid & 63;
    if (lane == 0) { sred[w] = s; ssred[w] = ss; }
    __syncthreads();
    s = sred[0] + sred[1] + sred[2] + sred[3];
    ss = ssred[0] + ssred[1] + ssred[2] + ssred[3];
    const float mean = s * (1.f / Dq);
    const float rstd = rsqrtf(ss * (1.f / Dq) - mean * mean + 1e-5f);
    float4 gv = ((const float4*)g)[tid];
    float4 bv = ((const float4*)bb)[tid];
    float4 o;
    o.x = (f0 - mean) * rstd * gv.x + bv.x;
    o.y = (f1 - mean) * rstd * gv.y + bv.y;
    o.z = (f2 - mean) * rstd * gv.z + bv.z;
    o.w = (f3 - mean) * rstd * gv.w + bv.w;
    ((float4*)out)[(size_t)row * 256 + tid] = o;
}

// ----------------------------------------------------------------- launch ---
extern "C" void kernel_launch(void* const* d_in, const int* in_sizes, int n_in,
                              void* d_out, int out_size, void* d_ws,
                              size_t ws_size, hipStream_t stream) {
    // 0 x, 1 padding_mask, 2 causal_mask(unused), 3 Wq, 4 bq, 5 Wk, 6 bk,
    // 7 Wv, 8 bv, 9 Wo, 10 bo, 11 g_pre, 12 b_pre, 13 g_ln, 14 b_ln
    const float* x = (const float*)d_in[0];
    const unsigned char* mask = (const unsigned char*)d_in[1];
    const float* Wq = (const float*)d_in[3];
    const float* bq = (const float*)d_in[4];
    const float* Wk = (const float*)d_in[5];
    const float* bk = (const float*)d_in[6];
    const float* Wv = (const float*)d_in[7];
    const float* bvv = (const float*)d_in[8];
    const float* Wo = (const float*)d_in[9];
    const float* bo = (const float*)d_in[10];
    const float* g_pre = (const float*)d_in[11];
    const float* b_pre = (const float*)d_in[12];
    const float* g_ln = (const float*)d_in[13];
    const float* b_ln = (const float*)d_in[14];

    const size_t SZ = (size_t)Mq * Dq;   // 8388608
    const size_t WSZ = (size_t)Dq * Dq;  // 1048576
    unsigned short* h = (unsigned short*)d_ws;
    unsigned short* q = h + SZ;
    unsigned short* k = q + SZ;
    unsigned short* vT = k + SZ;
    unsigned short* at = vT + SZ;
    unsigned short* W3 = at + SZ;        // [3072][1024] then Wo [1024][1024]
    unsigned short* wob = W3 + 3 * WSZ;
    float* proj = (float*)(wob + WSZ);
    int* lengths = (int*)(proj + SZ);

    prologue_kernel<<<4096 + Mq + 1, 256, 0, stream>>>(
        Wq, Wk, Wv, Wo, W3, x, g_pre, b_pre, h, mask, lengths);

    qkv_gemm_kernel<<<dim3(3 * Dq / 128, Mq / 128), 256, 0, stream>>>(
        h, W3, bq, bk, bvv, q, k, vT);
    attn_kernel<<<dim3(Lq / 256, Hq, Bq), 256, 0, stream>>>(q, k, vT, lengths,
                                                            at);
    proj_gemm_kernel<<<dim3(Dq / 128, Mq / 128), 256, 0, stream>>>(at, wob, bo,
                                                                   proj);
    ln_final_kernel<<<Mq, 256, 0, stream>>>(proj, h, g_ln, b_ln,
                                            (float*)d_out);
}

// Round 11
// 342.390 us; speedup vs baseline: 1.0134x; 1.0134x over previous
//
#include <hip/hip_runtime.h>

// B=4, L=2048, D=1024, H=16, HD=64. Inputs fp32, output fp32.
// All matmul math via mfma_f32_16x16x32_bf16, fp32 accumulation.
// v13 FINAL (consolidated best): attn is byte-exact v8 (92.1us measured:
// paired q-tiles, 4 waves x 32 q-rows, LDS-staged K/V dbuf + XOR swizzle,
// XCD-grouping, interleaved max accumulation, unconditional rescale placed
// inside the P^T LDS round-trip) + merged prologue (setup+cvt4+ln_pre, -10us)
// + 128^2 dbuf GEMMs with XCD swizzle.
// Session evidence: all attn structure variants (8x16-row waves, unpaired
// 1024 blocks, defer-rescale, exp2f, hoisted max-tree) measured WORSE;
// GEMM pipelining variants documented-null on the 2-barrier 128^2 structure;
// totals noise-bound at 345+-5us across identical configs.
// ws: h bf16 | q bf16 [bh][l][64] | k bf16 [bh][l][64] | vT bf16 [bh][d][L]
//     | attn bf16 [bh][l][64] | W3+Wo bf16 | proj fp32 | lengths.

#define Bq 4
#define Lq 2048
#define Dq 1024
#define Hq 16
#define HDq 64
#define Mq (Bq * Lq)  // 8192

typedef __attribute__((ext_vector_type(8))) short short8;
typedef __attribute__((ext_vector_type(4))) float f32x4;
typedef __attribute__((address_space(3))) unsigned char lds_byte;
typedef __attribute__((address_space(1))) unsigned char gbl_byte;

__device__ __forceinline__ unsigned short f2b(float f) {
    unsigned int u = __float_as_uint(f);
    unsigned int r = (u + 0x7fffu + ((u >> 16) & 1u)) >> 16;  // RNE
    return (unsigned short)r;
}
__device__ __forceinline__ float b2f(unsigned short u) {
    return __uint_as_float(((unsigned int)u) << 16);
}
__device__ __forceinline__ unsigned int packbf(float lo, float hi) {
    return (unsigned int)f2b(lo) | ((unsigned int)f2b(hi) << 16);
}

#define GLL16(gsrc, ldst)                                              \
    __builtin_amdgcn_global_load_lds((const gbl_byte*)(gsrc),          \
                                     (lds_byte*)(ldst), 16, 0, 0)

#define MFMA_BF16(A, B, C) \
    __builtin_amdgcn_mfma_f32_16x16x32_bf16((A), (B), (C), 0, 0, 0)

// --------------------------------------------------------------- prologue ---
// blocks [0,4096): cvt4 (f32->bf16 of Wq|Wk|Wv|Wo into W3 buffer)
// blocks [4096,12288): ln_pre row = bid-4096
// block 12288: setup (first-padded-column per batch row)
__global__ __launch_bounds__(256) void prologue_kernel(
    const float* __restrict__ s0, const float* __restrict__ s1,
    const float* __restrict__ s2, const float* __restrict__ s3,
    unsigned short* __restrict__ dst, const float* __restrict__ x,
    const float* __restrict__ g, const float* __restrict__ bb,
    unsigned short* __restrict__ out, const unsigned char* __restrict__ m8,
    int* __restrict__ lengths) {
    const int bid = blockIdx.x;
    const int tid = threadIdx.x;
    if (bid < 4096) {
        const int region = bid >> 10;  // 1024 blocks per weight
        const int i = (bid & 1023) * 256 + tid;
        const float* src = (region == 0) ? s0 : (region == 1) ? s1
                           : (region == 2) ? s2 : s3;
        float4 v = ((const float4*)src)[i];
        ushort4 o;
        o.x = f2b(v.x); o.y = f2b(v.y); o.z = f2b(v.z); o.w = f2b(v.w);
        ((ushort4*)dst)[(size_t)region * (Dq * Dq / 4) + i] = o;
        return;
    }
    if (bid < 4096 + Mq) {
        const int row = bid - 4096;
        float4 u = ((const float4*)x)[(size_t)row * 256 + tid];
        float s = u.x + u.y + u.z + u.w;
        float ss = u.x * u.x + u.y * u.y + u.z * u.z + u.w * u.w;
#pragma unroll
        for (int off = 32; off > 0; off >>= 1) {
            s += __shfl_xor(s, off);
            ss += __shfl_xor(ss, off);
        }
        __shared__ float sred[4], ssred[4];
        const int w = tid >> 6, lane = tid & 63;
        if (lane == 0) { sred[w] = s; ssred[w] = ss; }
        __syncthreads();
        s = sred[0] + sred[1] + sred[2] + sred[3];
        ss = ssred[0] + ssred[1] + ssred[2] + ssred[3];
        const float mean = s * (1.f / Dq);
        const float rstd = rsqrtf(ss * (1.f / Dq) - mean * mean + 1e-5f);
        float4 gv = ((const float4*)g)[tid];
        float4 bv = ((const float4*)bb)[tid];
        ushort4 o;
        o.x = f2b((u.x - mean) * rstd * gv.x + bv.x);
        o.y = f2b((u.y - mean) * rstd * gv.y + bv.y);
        o.z = f2b((u.z - mean) * rstd * gv.z + bv.z);
        o.w = f2b((u.w - mean) * rstd * gv.w + bv.w);
        ((ushort4*)out)[(size_t)row * 256 + tid] = o;
        return;
    }
    // setup
    __shared__ int bad;
    __shared__ int fo[4];
    if (tid == 0) bad = 0;
    if (tid < 4) fo[tid] = Lq;
    __syncthreads();
    for (int i = tid; i < Bq * Lq; i += 256) {
        unsigned char v = m8[i];
        if (v) {
            int r = i >> 11, c = i & (Lq - 1);
            atomicMin(&fo[r], c);
            if (c < Lq / 2) atomicOr(&bad, 1);
            else if (c < Lq - 1 && m8[i + 1] == 0) atomicOr(&bad, 1);
        }
    }
    __syncthreads();
    int anyone = (fo[0] < Lq) | (fo[1] < Lq) | (fo[2] < Lq) | (fo[3] < Lq);
    bool use8 = (bad == 0) && anyone;
    if (!use8) {
        __syncthreads();
        if (tid < 4) fo[tid] = Lq;
        __syncthreads();
        const int* m32 = (const int*)m8;
        for (int i = tid; i < Bq * Lq; i += 256) {
            if (m32[i] != 0) atomicMin(&fo[i >> 11], i & (Lq - 1));
        }
        __syncthreads();
    }
    if (tid < 4) lengths[tid] = fo[tid];
}

// -------------------------------------------------------- fused QKV GEMM ----
// C[8192][3072] = h @ [Wq;Wk;Wv]^T + bias. Q (pre-scaled by 1/8), K ->
// head-split [bh][l][64]; V -> transposed [bh][d][L]. XCD-swizzled blocks.
// Double-buffered LDS: STAGE(k+1) issued before compute(k); one barrier/iter.
__global__ __launch_bounds__(256) void qkv_gemm_kernel(
    const unsigned short* __restrict__ A, const unsigned short* __restrict__ W3,
    const float* __restrict__ bq, const float* __restrict__ bk,
    const float* __restrict__ bv, unsigned short* __restrict__ Qo,
    unsigned short* __restrict__ Ko, unsigned short* __restrict__ Vto) {
    __shared__ unsigned short As[2][128][32];
    __shared__ unsigned short Bs[2][128][32];
    const int tid = threadIdx.x;
    const int w = tid >> 6, lane = tid & 63;
    const int lm = lane & 15, lq = lane >> 4;
    // XCD-aware bijective swizzle (total blocks = 24*64 = 1536, %8 == 0)
    const int lin = blockIdx.y * 24 + blockIdx.x;
    const int swz = (lin & 7) * (1536 / 8) + (lin >> 3);
    const int m0 = (swz / 24) << 7, n0 = (swz % 24) << 7;  // n0 in [0,3072)
    const int wm = (w >> 1) << 6, wn = (w & 1) << 6;
    f32x4 acc[4][4];
#pragma unroll
    for (int i = 0; i < 4; ++i)
#pragma unroll
        for (int j = 0; j < 4; ++j) acc[i][j] = (f32x4){0.f, 0.f, 0.f, 0.f};

#define QKV_STAGE(BUF, K0)                                              \
    {                                                                   \
        _Pragma("unroll")                                               \
        for (int j = 0; j < 2; ++j) {                                   \
            const int base = j * 256 + w * 64;                          \
            const int slot = base + lane;                               \
            const int row = slot >> 2, c = slot & 3;                    \
            GLL16(A + (size_t)(m0 + row) * Dq + (K0) + c * 8,           \
                  (unsigned short*)As[BUF] + base * 8);                 \
            GLL16(W3 + (size_t)(n0 + row) * Dq + (K0) + c * 8,          \
                  (unsigned short*)Bs[BUF] + base * 8);                 \
        }                                                               \
    }

    QKV_STAGE(0, 0);
    __syncthreads();  // tile 0 resident
    for (int k0 = 0; k0 < Dq; k0 += 32) {
        const int cur = (k0 >> 5) & 1;
        if (k0 + 32 < Dq) QKV_STAGE(cur ^ 1, k0 + 32);  // prefetch next
        short8 af[4], bf[4];
#pragma unroll
        for (int t = 0; t < 4; ++t)
            af[t] = *(const short8*)&As[cur][wm + t * 16 + lm][lq * 8];
#pragma unroll
        for (int t = 0; t < 4; ++t)
            bf[t] = *(const short8*)&Bs[cur][wn + t * 16 + lm][lq * 8];
#pragma unroll
        for (int mt = 0; mt < 4; ++mt)
#pragma unroll
            for (int nt = 0; nt < 4; ++nt)
                acc[mt][nt] = __builtin_amdgcn_mfma_f32_16x16x32_bf16(
                    af[mt], bf[nt], acc[mt][nt], 0, 0, 0);
        __syncthreads();  // drains vmcnt (next tile resident), reads done
    }
#undef QKV_STAGE
    const int region = n0 >> 10;  // 0=Q 1=K 2=V (block-uniform)
    const float* bias = (region == 0) ? bq : (region == 1) ? bk : bv;
    const float scale = (region == 0) ? 0.125f : 1.0f;  // 1/sqrt(HD) into Q
    const int nb = n0 & 1023;
#pragma unroll
    for (int nt = 0; nt < 4; ++nt) {
        const int colb = nb + wn + nt * 16 + lm;  // 0..1023 within region
        const float bval = bias[colb];
#pragma unroll
        for (int mt = 0; mt < 4; ++mt) {
            const int row0 = m0 + wm + mt * 16 + lq * 4;
            const int bidx = row0 >> 11, l0r = row0 & (Lq - 1);
            if (region < 2) {
                unsigned short* dst = (region == 0) ? Qo : Ko;
#pragma unroll
                for (int r = 0; r < 4; ++r)
                    dst[((size_t)(bidx * Hq + (colb >> 6)) * Lq + l0r + r) *
                            HDq + (colb & 63)] =
                        f2b((acc[mt][nt][r] + bval) * scale);
            } else {
                ushort4 o;
                o.x = f2b(acc[mt][nt][0] + bval);
                o.y = f2b(acc[mt][nt][1] + bval);
                o.z = f2b(acc[mt][nt][2] + bval);
                o.w = f2b(acc[mt][nt][3] + bval);
                *(ushort4*)&Vto[((size_t)(bidx * Hq + (colb >> 6)) * HDq +
                                 (colb & 63)) * Lq + l0r] = o;
            }
        }
    }
}

// ------------------------------------------------------------- proj GEMM ----
// Double-buffered LDS with next-tile prefetch, as qkv.
__global__ __launch_bounds__(256) void proj_gemm_kernel(
    const unsigned short* __restrict__ A, const unsigned short* __restrict__ Bw,
    const float* __restrict__ bias, float* __restrict__ Cout) {
    __shared__ unsigned short As[2][128][32];
    __shared__ unsigned short Bs[2][128][32];
    const int tid = threadIdx.x;
    const int w = tid >> 6, lane = tid & 63;
    const int lm = lane & 15, lq = lane >> 4;
    // XCD-aware bijective swizzle (total blocks = 8*64 = 512, %8 == 0)
    const int lin = blockIdx.y * 8 + blockIdx.x;
    const int swz = (lin & 7) * (512 / 8) + (lin >> 3);
    const int m0 = (swz >> 3) << 7, n0 = (swz & 7) << 7;
    const int wm = (w >> 1) << 6, wn = (w & 1) << 6;
    f32x4 acc[4][4];
#pragma unroll
    for (int i = 0; i < 4; ++i)
#pragma unroll
        for (int j = 0; j < 4; ++j) acc[i][j] = (f32x4){0.f, 0.f, 0.f, 0.f};

#define PROJ_STAGE(BUF, K0)                                             \
    {                                                                   \
        _Pragma("unroll")                                               \
        for (int j = 0; j < 2; ++j) {                                   \
            const int base = j * 256 + w * 64;                          \
            const int slot = base + lane;                               \
            const int row = slot >> 2, c = slot & 3;                    \
            const int rr = m0 + row, kk = (K0) + c * 8;                 \
            GLL16(A + ((size_t)((rr >> 11) * Hq + (kk >> 6)) * Lq +     \
                       (rr & (Lq - 1))) * HDq + (kk & 63),              \
                  (unsigned short*)As[BUF] + base * 8);                 \
            GLL16(Bw + (size_t)(n0 + row) * Dq + (K0) + c * 8,          \
                  (unsigned short*)Bs[BUF] + base * 8);                 \
        }                                                               \
    }

    PROJ_STAGE(0, 0);
    __syncthreads();
    for (int k0 = 0; k0 < Dq; k0 += 32) {
        const int cur = (k0 >> 5) & 1;
        if (k0 + 32 < Dq) PROJ_STAGE(cur ^ 1, k0 + 32);
        short8 af[4], bf[4];
#pragma unroll
        for (int t = 0; t < 4; ++t)
            af[t] = *(const short8*)&As[cur][wm + t * 16 + lm][lq * 8];
#pragma unroll
        for (int t = 0; t < 4; ++t)
            bf[t] = *(const short8*)&Bs[cur][wn + t * 16 + lm][lq * 8];
#pragma unroll
        for (int mt = 0; mt < 4; ++mt)
#pragma unroll
            for (int nt = 0; nt < 4; ++nt)
                acc[mt][nt] = __builtin_amdgcn_mfma_f32_16x16x32_bf16(
                    af[mt], bf[nt], acc[mt][nt], 0, 0, 0);
        __syncthreads();
    }
#undef PROJ_STAGE
#pragma unroll
    for (int nt = 0; nt < 4; ++nt) {
        const float bval = bias[n0 + wn + nt * 16 + lm];
#pragma unroll
        for (int mt = 0; mt < 4; ++mt)
#pragma unroll
            for (int r = 0; r < 4; ++r)
                Cout[(size_t)(m0 + wm + mt * 16 + lq * 4 + r) * Dq + n0 + wn +
                     nt * 16 + lm] = acc[mt][nt][r] + bval;
    }
}

// ------------------------------------------------------- MFMA attention -----
// Byte-exact v8 (measured 92.1us): block = (q-tile pair, head, batch), 4
// waves; wave w owns q rows [w*32, w*32+32) of each 128-q tile as two
// 16-strips (q = lane&15). XCD-grouping: all 8 blocks of one (b,h) share an
// XCD -> K/V from its L2. Per kt, block stages K/V^T tiles into
// double-buffered LDS (global_load_lds dwordx4, 16B-chunk XOR swizzle via
// pre-swizzled global source + swizzled ds_read -> conflict-free b128).
// Both strips share one K/V fragment read and one lgkmcnt(0) per kt; the
// rescale VALU sits between the P^T write and its wait (latency filler).
// Max accumulation interleaved in the fill loop (scheduler filler).
// Q pre-scaled by 1/8 upstream; __expf softmax.
__global__ __launch_bounds__(256, 2) void attn_kernel(
    const unsigned short* __restrict__ Qg, const unsigned short* __restrict__ Kg,
    const unsigned short* __restrict__ Vtg, const int* __restrict__ lengths,
    unsigned short* __restrict__ Og) {
    __shared__ unsigned short Kbuf[2][4096];     // 2 x 8KB
    __shared__ unsigned short Vbuf[2][4096];     // 2 x 8KB
    __shared__ unsigned short Ps[4][2][16][72];  // per-wave-strip P^T (18KB)
    // XCD-grouping remap: lin = x + 8y + 128z; xcd = lin&7 (dispatch
    // round-robin); group g = xcd*8 + (sidx&7) so all 8 bx of g share an XCD.
    const int lin = blockIdx.x + (blockIdx.y << 3) + (blockIdx.z << 7);
    const int xcd = lin & 7, sidx = lin >> 3;
    const int grp = xcd * 8 + (sidx & 7);  // 0..63 = (b,h)
    const int bx = sidx >> 3;              // 0..7 q-tile pair index
    const int hh = grp & 15, b = grp >> 4;
    const int tid = threadIdx.x, w = tid >> 6, lane = tid & 63;
    const int lm = lane & 15, lq = lane >> 4;
    const int len = lengths[b];
    const int mxk = (len + 63) >> 6;
    const size_t hb = (size_t)(b * Hq + hh) * Lq * HDq;  // Q,K,O base
    const unsigned short* Vb = Vtg + hb;                  // [d][L]

    // staging: thread covers chunk L = r*256 + w*64 + lane of each 512-chunk
    // (16B) tile; row = L>>3, stored slot = L&7, fetched slot =
    // (L&7) ^ (row&7)  [XOR bijection per row]
    const int srow = w * 8 + (lane >> 3);             // rows 0..31 (r=1: +32)
    const int ssw = (lane & 7) ^ (lane >> 3);         // swizzled source slot
    const unsigned short* pK = Kg + hb + (size_t)srow * HDq + ssw * 8;
    const unsigned short* pV = Vb + (size_t)srow * Lq + ssw * 8;

#define STAGE_KV(BUF, KB)                                                   \
    {                                                                       \
        GLL16(pK + (size_t)(KB)*HDq, &Kbuf[(BUF)][(w * 64) * 8]);           \
        GLL16(pK + (size_t)((KB) + 32) * HDq,                               \
              &Kbuf[(BUF)][(256 + w * 64) * 8]);                            \
        GLL16(pV + (KB), &Vbuf[(BUF)][(w * 64) * 8]);                       \
        GLL16(pV + (size_t)32 * Lq + (KB),                                  \
              &Vbuf[(BUF)][(256 + w * 64) * 8]);                            \
    }

#pragma unroll
    for (int pass = 0; pass < 2; ++pass) {
        const int qt = pass ? bx : (15 - bx);  // pair: total work uniform
        const int l0 = qt << 7;
        // Q fragments: direct register loads
        short8 qf[2][2];
#pragma unroll
        for (int s = 0; s < 2; ++s)
#pragma unroll
            for (int h = 0; h < 2; ++h)
                qf[s][h] = *(const short8*)(Qg + hb +
                    (size_t)(l0 + w * 32 + s * 16 + lm) * HDq + h * 32 + lq * 8);
        f32x4 oacc[2][4];
        float m_i[2], l_i[2];
#pragma unroll
        for (int s = 0; s < 2; ++s) {
            m_i[s] = -1e30f; l_i[s] = 0.f;
#pragma unroll
            for (int t = 0; t < 4; ++t)
                oacc[s][t] = (f32x4){0.f, 0.f, 0.f, 0.f};
        }
        int nkt = 2 * qt + 2;
        if (nkt > mxk) nkt = mxk;
        // prologue: stage kt=0 into buf 0 (nkt >= 2 always since len >= L/2)
        STAGE_KV(0, 0);
        __syncthreads();  // drains vmcnt -> tile 0 resident
        for (int kt = 0; kt < nkt; ++kt) {
            const int kb = kt << 6;
            const int cur = kt & 1;
            if (kt + 1 < nkt) STAGE_KV(cur ^ 1, (kt + 1) << 6);
            // fragments from LDS (swizzled chunk index, conflict-free b128)
            short8 kf[4][2], vf[4][2];
#pragma unroll
            for (int t = 0; t < 4; ++t) {
                const int ro = (t * 16 + lm) * 64;
                const int sx = lm & 7;
#pragma unroll
                for (int h = 0; h < 2; ++h) {
                    const int off = ro + (((h * 4 + lq) ^ sx) << 3);
                    kf[t][h] = *(const short8*)&Kbuf[cur][off];
                    vf[t][h] = *(const short8*)&Vbuf[cur][off];
                }
            }
            f32x4 sc[2][4];
            __builtin_amdgcn_s_setprio(1);
#pragma unroll
            for (int s = 0; s < 2; ++s) {
#pragma unroll
                for (int t = 0; t < 4; ++t) {  // S^T = K Q^T
                    f32x4 z = (f32x4){0.f, 0.f, 0.f, 0.f};
                    z = MFMA_BF16(kf[t][0], qf[s][0], z);
                    z = MFMA_BF16(kf[t][1], qf[s][1], z);
                    sc[s][t] = z;
                }
            }
            __builtin_amdgcn_s_setprio(0);
#pragma unroll
            for (int s = 0; s < 2; ++s) {
                const int qmin = l0 + w * 32 + s * 16;
                float pvv[16];
                float mx = -1e30f;
                if ((kb + 63 <= qmin) && (kb + 63 < len)) {  // interior
#pragma unroll
                    for (int i = 0; i < 16; ++i) {
                        const float v = sc[s][i >> 2][i & 3];
                        pvv[i] = v;
                        mx = fmaxf(mx, v);
                    }
                } else {
                    const int qq = qmin + lm;
#pragma unroll
                    for (int t = 0; t < 4; ++t)
#pragma unroll
                        for (int r = 0; r < 4; ++r) {
                            const int key = kb + t * 16 + lq * 4 + r;
                            float v = sc[s][t][r];
                            if (key > qq || key >= len) v = -1e30f;
                            pvv[t * 4 + r] = v;
                            mx = fmaxf(mx, v);
                        }
                }
                mx = fmaxf(mx, __shfl_xor(mx, 16));
                mx = fmaxf(mx, __shfl_xor(mx, 32));
                const float mnew = fmaxf(m_i[s], mx);
                float psum = 0.f;
#pragma unroll
                for (int i = 0; i < 16; ++i) {
                    const float p = __expf(pvv[i] - mnew);
                    pvv[i] = p;
                    psum += p;
                }
                // P^T C-layout -> B-layout via per-wave-strip LDS scratch
#pragma unroll
                for (int t = 0; t < 4; ++t) {
                    uint2 uu;
                    uu.x = packbf(pvv[t * 4 + 0], pvv[t * 4 + 1]);
                    uu.y = packbf(pvv[t * 4 + 2], pvv[t * 4 + 3]);
                    *(uint2*)&Ps[w][s][lm][t * 16 + lq * 4] = uu;
                }
                psum += __shfl_xor(psum, 16);
                psum += __shfl_xor(psum, 32);
                const float alpha = __expf(m_i[s] - mnew);
                m_i[s] = mnew;
                l_i[s] = l_i[s] * alpha + psum;
#pragma unroll
                for (int t = 0; t < 4; ++t) {
                    oacc[s][t][0] *= alpha; oacc[s][t][1] *= alpha;
                    oacc[s][t][2] *= alpha; oacc[s][t][3] *= alpha;
                }
            }
            asm volatile("s_waitcnt lgkmcnt(0)" ::: "memory");
            __builtin_amdgcn_s_setprio(1);
#pragma unroll
            for (int s = 0; s < 2; ++s) {
                short8 pf0 = *(const short8*)&Ps[w][s][lm][lq * 8];
                short8 pf1 = *(const short8*)&Ps[w][s][lm][32 + lq * 8];
#pragma unroll
                for (int t = 0; t < 4; ++t) {  // O^T += V^T P^T
                    oacc[s][t] = MFMA_BF16(vf[t][0], pf0, oacc[s][t]);
                    oacc[s][t] = MFMA_BF16(vf[t][1], pf1, oacc[s][t]);
                }
            }
            __builtin_amdgcn_s_setprio(0);
            __syncthreads();  // staged kt+1 resident; buf[cur] reads done
        }
#pragma unroll
        for (int s = 0; s < 2; ++s) {
            const float inv = 1.f / l_i[s];
            unsigned short* Ot =
                Og + hb + (size_t)(l0 + w * 32 + s * 16 + lm) * HDq;
#pragma unroll
            for (int t = 0; t < 4; ++t) {
                ushort4 o;
                o.x = f2b(oacc[s][t][0] * inv);
                o.y = f2b(oacc[s][t][1] * inv);
                o.z = f2b(oacc[s][t][2] * inv);
                o.w = f2b(oacc[s][t][3] * inv);
                *(ushort4*)(Ot + t * 16 + lq * 4) = o;
            }
        }
    }
#undef STAGE_KV
}

// ------------------------------------------------------------------- LN 2 ---
__global__ __launch_bounds__(256) void ln_final_kernel(
    const float* __restrict__ pj, const unsigned short* __restrict__ h,
    const float* __restrict__ g, const float* __restrict__ bb,
    float* __restrict__ out) {
    const int row = blockIdx.x, tid = threadIdx.x;
    float4 a = ((const float4*)pj)[(size_t)row * 256 + tid];
    ushort4 hv = ((const ushort4*)h)[(size_t)row * 256 + tid];
    float f0 = a.x + b2f(hv.x), f1 = a.y + b2f(hv.y);
    float f2 = a.z + b2f(hv.z), f3 = a.w + b2f(hv.w);
    float s = f0 + f1 + f2 + f3;
    float ss = f0 * f0 + f1 * f1 + f2 * f2 + f3 * f3;
#pragma unroll
    for (int off = 32; off > 0; off >>= 1) {
        s += __shfl_xor(s, off);
        ss += __shfl_xor(ss, off);
    }
    __shared__ float sred[4], ssred[4];
    const int w = tid >> 6, lane = tid & 63;
    if (lane == 0) { sred[w] = s; ssred[w] = ss; }
    __syncthreads();
    s = sred[0] + sred[1] + sred[2] + sred[3];
    ss = ssred[0] + ssred[1] + ssred[2] + ssred[3];
    const float mean = s * (1.f / Dq);
    const float rstd = rsqrtf(ss * (1.f / Dq) - mean * mean + 1e-5f);
    float4 gv = ((const float4*)g)[tid];
    float4 bv = ((const float4*)bb)[tid];
    float4 o;
    o.x = (f0 - mean) * rstd * gv.x + bv.x;
    o.y = (f1 - mean) * rstd * gv.y + bv.y;
    o.z = (f2 - mean) * rstd * gv.z + bv.z;
    o.w = (f3 - mean) * rstd * gv.w + bv.w;
    ((float4*)out)[(size_t)row * 256 + tid] = o;
}

// ----------------------------------------------------------------- launch ---
extern "C" void kernel_launch(void* const* d_in, const int* in_sizes, int n_in,
                              void* d_out, int out_size, void* d_ws,
                              size_t ws_size, hipStream_t stream) {
    // 0 x, 1 padding_mask, 2 causal_mask(unused), 3 Wq, 4 bq, 5 Wk, 6 bk,
    // 7 Wv, 8 bv, 9 Wo, 10 bo, 11 g_pre, 12 b_pre, 13 g_ln, 14 b_ln
    const float* x = (const float*)d_in[0];
    const unsigned char* mask = (const unsigned char*)d_in[1];
    const float* Wq = (const float*)d_in[3];
    const float* bq = (const float*)d_in[4];
    const float* Wk = (const float*)d_in[5];
    const float* bk = (const float*)d_in[6];
    const float* Wv = (const float*)d_in[7];
    const float* bvv = (const float*)d_in[8];
    const float* Wo = (const float*)d_in[9];
    const float* bo = (const float*)d_in[10];
    const float* g_pre = (const float*)d_in[11];
    const float* b_pre = (const float*)d_in[12];
    const float* g_ln = (const float*)d_in[13];
    const float* b_ln = (const float*)d_in[14];

    const size_t SZ = (size_t)Mq * Dq;   // 8388608
    const size_t WSZ = (size_t)Dq * Dq;  // 1048576
    unsigned short* h = (unsigned short*)d_ws;
    unsigned short* q = h + SZ;
    unsigned short* k = q + SZ;
    unsigned short* vT = k + SZ;
    unsigned short* at = vT + SZ;
    unsigned short* W3 = at + SZ;        // [3072][1024] then Wo [1024][1024]
    unsigned short* wob = W3 + 3 * WSZ;
    float* proj = (float*)(wob + WSZ);
    int* lengths = (int*)(proj + SZ);

    prologue_kernel<<<4096 + Mq + 1, 256, 0, stream>>>(
        Wq, Wk, Wv, Wo, W3, x, g_pre, b_pre, h, mask, lengths);

    qkv_gemm_kernel<<<dim3(3 * Dq / 128, Mq / 128), 256, 0, stream>>>(
        h, W3, bq, bk, bvv, q, k, vT);
    attn_kernel<<<dim3(Lq / 256, Hq, Bq), 256, 0, stream>>>(q, k, vT, lengths,
                                                            at);
    proj_gemm_kernel<<<dim3(Dq / 128, Mq / 128), 256, 0, stream>>>(at, wob, bo,
                                                                   proj);
    ln_final_kernel<<<Mq, 256, 0, stream>>>(proj, h, g_ln, b_ln,
                                            (float*)d_out);
}